// Round 4
// baseline (202.566 us; speedup 1.0000x reference)
//
#include <hip/hip_runtime.h>
#include <math.h>

#define N 1024
#define D 64
#define ALPHA 0.2f
#define LN_EPS 1e-5f
#define MASK_VAL -1000000000.0f

typedef __attribute__((ext_vector_type(8))) short bf16x8;
typedef __attribute__((ext_vector_type(4))) float f32x4;

__device__ __forceinline__ float leaky(float x) { return fmaxf(x, ALPHA * x); }

// scalar f32 -> bf16 RNE
__device__ __forceinline__ unsigned f2bf_u(float f) {
    unsigned u = __builtin_bit_cast(unsigned, f);
    u += 0x7fffu + ((u >> 16) & 1u);
    return u >> 16;          // bf16 bits in low 16
}
__device__ __forceinline__ short f2bf(float f) { return (short)f2bf_u(f); }

// leaky + bf16 convert two elements -> one packed dword (y in high 16)
__device__ __forceinline__ unsigned lpk(float x, float y) {
    float lx = fmaxf(x, ALPHA * x);
    float ly = fmaxf(y, ALPHA * y);
    return f2bf_u(lx) | (f2bf_u(ly) << 16);
}

union BF8 { bf16x8 v; unsigned u[4]; };

// ---------------------------------------------------------------------------
// Kernel 1: row-wise projections (4 rows per block).
// ---------------------------------------------------------------------------
__global__ __launch_bounds__(256) void gat_precompute(
    const float* __restrict__ h, const float* __restrict__ W,
    const float* __restrict__ attn_w1, const float* __restrict__ attn_b1,
    const float* __restrict__ edge_w, const float* __restrict__ edge_b,
    float* __restrict__ Wh, float* __restrict__ ejB, float* __restrict__ aj,
    float* __restrict__ ei, float* __restrict__ aiB)
{
    const int tid = threadIdx.x;
    const int r = tid >> 6;
    const int k = tid & 63;
    const int i = blockIdx.x * 4 + r;
    __shared__ float hrow[4][D];
    __shared__ float whrow[4][D];

    hrow[r][k] = h[(size_t)i * D + k];
    __syncthreads();

    float wh = 0.f, vei = 0.f, vej = 0.f;
    #pragma unroll 8
    for (int m = 0; m < D; ++m) {
        float hm = hrow[r][m];
        wh  = fmaf(hm, W[m * D + k], wh);
        vei = fmaf(hm, edge_w[m * D + k], vei);
        vej = fmaf(hm, edge_w[(m + D) * D + k], vej);
    }
    Wh[(size_t)i * D + k]  = wh;
    ei[(size_t)i * D + k]  = vei;
    ejB[(size_t)i * D + k] = vej + edge_b[k];
    whrow[r][k] = wh;
    __syncthreads();

    float vai = 0.f, vaj = 0.f;
    #pragma unroll 8
    for (int m = 0; m < D; ++m) {
        float wm = whrow[r][m];
        vai = fmaf(wm, attn_w1[m * D + k], vai);
        vaj = fmaf(wm, attn_w1[(m + D) * D + k], vaj);
    }
    aiB[(size_t)i * D + k] = vai + attn_b1[k];
    aj[(size_t)i * D + k]  = vaj;
}

// ---------------------------------------------------------------------------
// Kernel 2: scores. Block = 4 i's x 256 j's. grid = (1024/4)*(1024/256)=1024.
// Wave handles 64 j's (4 j-tiles of 16). j-side loads reused across 4 i's.
// e_out[i*N+j] = w2 . leaky(P + aj[j] + aiB[i]) + b2   (unmasked)
// ---------------------------------------------------------------------------
__global__ __launch_bounds__(256, 4) void gat_scores(
    const float* __restrict__ ejB, const float* __restrict__ aj,
    const float* __restrict__ ei, const float* __restrict__ aiB,
    const float* __restrict__ attn_w1, const float* __restrict__ attn_w2,
    const float* __restrict__ attn_b2, float* __restrict__ e_out)
{
    const int tid  = threadIdx.x;
    const int lane = tid & 63;
    const int wid  = tid >> 6;
    const int nloc = lane & 15;
    const int quad = lane >> 4;
    const int i0   = (blockIdx.x >> 2) * 4;
    const int jb   = (blockIdx.x & 3) * 256 + wid * 64;
    const float* __restrict__ Ae = attn_w1 + 128 * D;

    __shared__ __align__(16) float sv[4][D];   // ei rows
    __shared__ float av[4][D];                 // aiB rows

    sv[tid >> 6][tid & 63] = ei[(size_t)(i0 + (tid >> 6)) * D + (tid & 63)];
    av[tid >> 6][tid & 63] = aiB[(size_t)(i0 + (tid >> 6)) * D + (tid & 63)];
    __syncthreads();

    // B fragments (A_e, bf16) resident per wave
    bf16x8 Bf[2][4];
    #pragma unroll
    for (int kt = 0; kt < 2; ++kt)
        #pragma unroll
        for (int ot = 0; ot < 4; ++ot)
            #pragma unroll
            for (int idx = 0; idx < 8; ++idx) {
                int k = kt * 32 + quad * 8 + idx;
                Bf[kt][ot][idx] = f2bf(Ae[(size_t)k * D + ot * 16 + nloc]);
            }

    float w2l[4];
    #pragma unroll
    for (int ot = 0; ot < 4; ++ot) w2l[ot] = attn_w2[ot * 16 + nloc];
    const float b2 = attn_b2[0];

    for (int jt = 0; jt < 4; ++jt) {
        const int j16 = jb + jt * 16;
        const float* __restrict__ ejr = ejB + (size_t)(j16 + nloc) * D;

        // j-side loads, reused over 4 i's
        const int k0 = quad * 8;
        float4 ev0 = *(const float4*)(ejr + k0);
        float4 ev1 = *(const float4*)(ejr + k0 + 4);
        float4 ev2 = *(const float4*)(ejr + 32 + k0);
        float4 ev3 = *(const float4*)(ejr + 32 + k0 + 4);

        f32x4 ajreg[4];
        #pragma unroll
        for (int ot = 0; ot < 4; ++ot)
            #pragma unroll
            for (int r = 0; r < 4; ++r)
                ajreg[ot][r] = aj[(size_t)(j16 + quad * 4 + r) * D + ot * 16 + nloc];

        #pragma unroll
        for (int ii = 0; ii < 4; ++ii) {
            const float4 s0 = *(const float4*)(&sv[ii][k0]);
            const float4 s1 = *(const float4*)(&sv[ii][k0 + 4]);
            const float4 s2 = *(const float4*)(&sv[ii][32 + k0]);
            const float4 s3 = *(const float4*)(&sv[ii][32 + k0 + 4]);

            BF8 af0, af1;
            af0.u[0] = lpk(ev0.x + s0.x, ev0.y + s0.y);
            af0.u[1] = lpk(ev0.z + s0.z, ev0.w + s0.w);
            af0.u[2] = lpk(ev1.x + s1.x, ev1.y + s1.y);
            af0.u[3] = lpk(ev1.z + s1.z, ev1.w + s1.w);
            af1.u[0] = lpk(ev2.x + s2.x, ev2.y + s2.y);
            af1.u[1] = lpk(ev2.z + s2.z, ev2.w + s2.w);
            af1.u[2] = lpk(ev3.x + s3.x, ev3.y + s3.y);
            af1.u[3] = lpk(ev3.z + s3.z, ev3.w + s3.w);

            f32x4 acc[4];
            #pragma unroll
            for (int ot = 0; ot < 4; ++ot) {
                acc[ot] = __builtin_amdgcn_mfma_f32_16x16x32_bf16(af0.v, Bf[0][ot], ajreg[ot], 0, 0, 0);
                acc[ot] = __builtin_amdgcn_mfma_f32_16x16x32_bf16(af1.v, Bf[1][ot], acc[ot], 0, 0, 0);
            }

            float part[4] = {0.f, 0.f, 0.f, 0.f};
            #pragma unroll
            for (int ot = 0; ot < 4; ++ot) {
                const float avli = av[ii][ot * 16 + nloc];
                #pragma unroll
                for (int r = 0; r < 4; ++r) {
                    float pre = acc[ot][r] + avli;
                    part[r] = fmaf(leaky(pre), w2l[ot], part[r]);
                }
            }
            #pragma unroll
            for (int r = 0; r < 4; ++r) {
                float v = part[r];
                v += __shfl_xor(v, 1, 64);
                v += __shfl_xor(v, 2, 64);
                v += __shfl_xor(v, 4, 64);
                v += __shfl_xor(v, 8, 64);
                part[r] = v;
            }
            if (nloc == 0) {
                const int jr = j16 + quad * 4;
                #pragma unroll
                for (int r = 0; r < 4; ++r)
                    e_out[(size_t)(i0 + ii) * N + jr + r] = part[r] + b2;
            }
        }
    }
}

// ---------------------------------------------------------------------------
// Kernel 3: mask + softmax + aggregation + layernorm. Block = 4 rows.
// ---------------------------------------------------------------------------
__global__ __launch_bounds__(256) void gat_softagg(
    const float* __restrict__ e_in, const int* __restrict__ adj,
    const float* __restrict__ Wh, const float* __restrict__ h,
    const float* __restrict__ ln_g, const float* __restrict__ ln_b,
    float* __restrict__ out)
{
    const int tid  = threadIdx.x;
    const int lane = tid & 63;
    const int wid  = tid >> 6;
    const int i0   = blockIdx.x * 4;
    const int i    = i0 + wid;

    __shared__ float p[4][N];       // 16 KB
    __shared__ float invs[4];
    __shared__ float red[4][4][D];  // [jgroup][row][ch] 4 KB

    // --- per-wave softmax for row i ---------------------------------------
    {
        const float* __restrict__ erow = e_in + (size_t)i * N;
        const int*   __restrict__ arow = adj  + (size_t)i * N;
        float m = -INFINITY;
        #pragma unroll 4
        for (int c = 0; c < N / 64; ++c) {
            int j = c * 64 + lane;
            float v = erow[j];
            if (arow[j] == 0) v = MASK_VAL;
            p[wid][j] = v;
            m = fmaxf(m, v);
        }
        #pragma unroll
        for (int off = 32; off >= 1; off >>= 1) m = fmaxf(m, __shfl_xor(m, off, 64));
        float s = 0.f;
        #pragma unroll 4
        for (int c = 0; c < N / 64; ++c) {
            int j = c * 64 + lane;
            float pv = __expf(p[wid][j] - m);
            p[wid][j] = pv;
            s += pv;
        }
        #pragma unroll
        for (int off = 32; off >= 1; off >>= 1) s += __shfl_xor(s, off, 64);
        if (lane == 0) invs[wid] = 1.f / s;
    }
    __syncthreads();

    // --- aggregation: thread = (channel k, j-group g); Wh load shared ------
    {
        const int k = tid & 63, g = tid >> 6;
        float hp0 = 0.f, hp1 = 0.f, hp2 = 0.f, hp3 = 0.f;
        #pragma unroll 4
        for (int jj = 0; jj < 256; ++jj) {
            const int j = g * 256 + jj;
            const float whv = Wh[(size_t)j * D + k];
            hp0 = fmaf(p[0][j], whv, hp0);
            hp1 = fmaf(p[1][j], whv, hp1);
            hp2 = fmaf(p[2][j], whv, hp2);
            hp3 = fmaf(p[3][j], whv, hp3);
        }
        red[g][0][k] = hp0;
        red[g][1][k] = hp1;
        red[g][2][k] = hp2;
        red[g][3][k] = hp3;
    }
    __syncthreads();

    // --- final: wave wid -> row i; lane = channel --------------------------
    {
        float v = (red[0][wid][lane] + red[1][wid][lane] +
                   red[2][wid][lane] + red[3][wid][lane]) * invs[wid]
                  + h[(size_t)i * D + lane];
        float mu = v;
        #pragma unroll
        for (int off = 32; off >= 1; off >>= 1) mu += __shfl_xor(mu, off, 64);
        mu *= (1.f / D);
        float d = v - mu;
        float var = d * d;
        #pragma unroll
        for (int off = 32; off >= 1; off >>= 1) var += __shfl_xor(var, off, 64);
        var *= (1.f / D);
        out[(size_t)i * D + lane] = d * rsqrtf(var + LN_EPS) * ln_g[lane] + ln_b[lane];
    }
}

// ---------------------------------------------------------------------------
extern "C" void kernel_launch(void* const* d_in, const int* in_sizes, int n_in,
                              void* d_out, int out_size, void* d_ws, size_t ws_size,
                              hipStream_t stream) {
    const float* h       = (const float*)d_in[0];
    const int*   adj     = (const int*)  d_in[1];
    const float* W       = (const float*)d_in[2];
    const float* attn_w1 = (const float*)d_in[3];
    const float* attn_b1 = (const float*)d_in[4];
    const float* attn_w2 = (const float*)d_in[5];
    const float* attn_b2 = (const float*)d_in[6];
    const float* edge_w  = (const float*)d_in[7];
    const float* edge_b  = (const float*)d_in[8];
    const float* ln_g    = (const float*)d_in[9];
    const float* ln_b    = (const float*)d_in[10];
    float* out = (float*)d_out;

    float* ws  = (float*)d_ws;
    float* Wh  = ws + 0 * (N * D);
    float* ejB = ws + 1 * (N * D);
    float* aj  = ws + 2 * (N * D);
    float* ei  = ws + 3 * (N * D);
    float* aiB = ws + 4 * (N * D);
    float* e   = ws + 5 * (N * D);   // N*N floats = 4 MB

    gat_precompute<<<N / 4, 256, 0, stream>>>(h, W, attn_w1, attn_b1, edge_w, edge_b,
                                              Wh, ejB, aj, ei, aiB);
    gat_scores<<<(N / 4) * 4, 256, 0, stream>>>(ejB, aj, ei, aiB,
                                                attn_w1, attn_w2, attn_b2, e);
    gat_softagg<<<N / 4, 256, 0, stream>>>(e, adj, Wh, h, ln_g, ln_b, out);
}

// Round 5
// 138.620 us; speedup vs baseline: 1.4613x; 1.4613x over previous
//
#include <hip/hip_runtime.h>
#include <math.h>

#define N 1024
#define D 64
#define ALPHA 0.2f
#define LN_EPS 1e-5f
#define MASK_VAL -1000000000.0f

typedef __attribute__((ext_vector_type(8))) short bf16x8;
typedef __attribute__((ext_vector_type(4))) float f32x4;

__device__ __forceinline__ float leaky(float x) { return fmaxf(x, ALPHA * x); }

// scalar f32 -> bf16 RNE
__device__ __forceinline__ unsigned f2bf_u(float f) {
    unsigned u = __builtin_bit_cast(unsigned, f);
    u += 0x7fffu + ((u >> 16) & 1u);
    return u >> 16;          // bf16 bits in low 16
}
__device__ __forceinline__ short f2bf(float f) { return (short)f2bf_u(f); }

// leaky + bf16 convert two elements -> one packed dword (y in high 16)
__device__ __forceinline__ unsigned lpk(float x, float y) {
    float lx = fmaxf(x, ALPHA * x);
    float ly = fmaxf(y, ALPHA * y);
    return f2bf_u(lx) | (f2bf_u(ly) << 16);
}

union BF8 { bf16x8 v; unsigned u[4]; };

// ---------------------------------------------------------------------------
// Kernel 1: row-wise projections (4 rows per block).
// ---------------------------------------------------------------------------
__global__ __launch_bounds__(256) void gat_precompute(
    const float* __restrict__ h, const float* __restrict__ W,
    const float* __restrict__ attn_w1, const float* __restrict__ attn_b1,
    const float* __restrict__ edge_w, const float* __restrict__ edge_b,
    float* __restrict__ Wh, float* __restrict__ ejB, float* __restrict__ aj,
    float* __restrict__ ei, float* __restrict__ aiB)
{
    const int tid = threadIdx.x;
    const int r = tid >> 6;
    const int k = tid & 63;
    const int i = blockIdx.x * 4 + r;
    __shared__ float hrow[4][D];
    __shared__ float whrow[4][D];

    hrow[r][k] = h[(size_t)i * D + k];
    __syncthreads();

    float wh = 0.f, vei = 0.f, vej = 0.f;
    #pragma unroll 8
    for (int m = 0; m < D; ++m) {
        float hm = hrow[r][m];
        wh  = fmaf(hm, W[m * D + k], wh);
        vei = fmaf(hm, edge_w[m * D + k], vei);
        vej = fmaf(hm, edge_w[(m + D) * D + k], vej);
    }
    Wh[(size_t)i * D + k]  = wh;
    ei[(size_t)i * D + k]  = vei;
    ejB[(size_t)i * D + k] = vej + edge_b[k];
    whrow[r][k] = wh;
    __syncthreads();

    float vai = 0.f, vaj = 0.f;
    #pragma unroll 8
    for (int m = 0; m < D; ++m) {
        float wm = whrow[r][m];
        vai = fmaf(wm, attn_w1[m * D + k], vai);
        vaj = fmaf(wm, attn_w1[(m + D) * D + k], vaj);
    }
    aiB[(size_t)i * D + k] = vai + attn_b1[k];
    aj[(size_t)i * D + k]  = vaj;
}

// ---------------------------------------------------------------------------
// Kernel 2: scores. Block = 4 i's x 256 j's. grid = (1024/4)*(1024/256)=1024.
// Wave handles 64 j's (4 j-tiles of 16). j-side loads reused across 4 i's.
// NOTE: no min-waves bound — R4's (256,4) capped regs at 128 and spilled
// ~76 MB/dispatch to scratch. Let the allocator take ~160 regs, 3 waves/SIMD.
// ---------------------------------------------------------------------------
__global__ __launch_bounds__(256) void gat_scores(
    const float* __restrict__ ejB, const float* __restrict__ aj,
    const float* __restrict__ ei, const float* __restrict__ aiB,
    const float* __restrict__ attn_w1, const float* __restrict__ attn_w2,
    const float* __restrict__ attn_b2, float* __restrict__ e_out)
{
    const int tid  = threadIdx.x;
    const int lane = tid & 63;
    const int wid  = tid >> 6;
    const int nloc = lane & 15;
    const int quad = lane >> 4;
    const int i0   = (blockIdx.x >> 2) * 4;
    const int jb   = (blockIdx.x & 3) * 256 + wid * 64;
    const float* __restrict__ Ae = attn_w1 + 128 * D;

    __shared__ __align__(16) float sv[4][D];   // ei rows
    __shared__ float av[4][D];                 // aiB rows

    sv[tid >> 6][tid & 63] = ei[(size_t)(i0 + (tid >> 6)) * D + (tid & 63)];
    av[tid >> 6][tid & 63] = aiB[(size_t)(i0 + (tid >> 6)) * D + (tid & 63)];
    __syncthreads();

    // B fragments (A_e, bf16) resident per wave
    bf16x8 Bf[2][4];
    #pragma unroll
    for (int kt = 0; kt < 2; ++kt)
        #pragma unroll
        for (int ot = 0; ot < 4; ++ot)
            #pragma unroll
            for (int idx = 0; idx < 8; ++idx) {
                int k = kt * 32 + quad * 8 + idx;
                Bf[kt][ot][idx] = f2bf(Ae[(size_t)k * D + ot * 16 + nloc]);
            }

    float w2l[4];
    #pragma unroll
    for (int ot = 0; ot < 4; ++ot) w2l[ot] = attn_w2[ot * 16 + nloc];
    const float b2 = attn_b2[0];

    for (int jt = 0; jt < 4; ++jt) {
        const int j16 = jb + jt * 16;
        const float* __restrict__ ejr = ejB + (size_t)(j16 + nloc) * D;

        // j-side loads, reused over 4 i's
        const int k0 = quad * 8;
        float4 ev0 = *(const float4*)(ejr + k0);
        float4 ev1 = *(const float4*)(ejr + k0 + 4);
        float4 ev2 = *(const float4*)(ejr + 32 + k0);
        float4 ev3 = *(const float4*)(ejr + 32 + k0 + 4);

        f32x4 ajreg[4];
        #pragma unroll
        for (int ot = 0; ot < 4; ++ot)
            #pragma unroll
            for (int r = 0; r < 4; ++r)
                ajreg[ot][r] = aj[(size_t)(j16 + quad * 4 + r) * D + ot * 16 + nloc];

        #pragma unroll
        for (int ii = 0; ii < 4; ++ii) {
            const float4 s0 = *(const float4*)(&sv[ii][k0]);
            const float4 s1 = *(const float4*)(&sv[ii][k0 + 4]);
            const float4 s2 = *(const float4*)(&sv[ii][32 + k0]);
            const float4 s3 = *(const float4*)(&sv[ii][32 + k0 + 4]);

            BF8 af0, af1;
            af0.u[0] = lpk(ev0.x + s0.x, ev0.y + s0.y);
            af0.u[1] = lpk(ev0.z + s0.z, ev0.w + s0.w);
            af0.u[2] = lpk(ev1.x + s1.x, ev1.y + s1.y);
            af0.u[3] = lpk(ev1.z + s1.z, ev1.w + s1.w);
            af1.u[0] = lpk(ev2.x + s2.x, ev2.y + s2.y);
            af1.u[1] = lpk(ev2.z + s2.z, ev2.w + s2.w);
            af1.u[2] = lpk(ev3.x + s3.x, ev3.y + s3.y);
            af1.u[3] = lpk(ev3.z + s3.z, ev3.w + s3.w);

            f32x4 acc[4];
            #pragma unroll
            for (int ot = 0; ot < 4; ++ot) {
                acc[ot] = __builtin_amdgcn_mfma_f32_16x16x32_bf16(af0.v, Bf[0][ot], ajreg[ot], 0, 0, 0);
                acc[ot] = __builtin_amdgcn_mfma_f32_16x16x32_bf16(af1.v, Bf[1][ot], acc[ot], 0, 0, 0);
            }

            float part[4] = {0.f, 0.f, 0.f, 0.f};
            #pragma unroll
            for (int ot = 0; ot < 4; ++ot) {
                const float avli = av[ii][ot * 16 + nloc];
                #pragma unroll
                for (int r = 0; r < 4; ++r) {
                    float pre = acc[ot][r] + avli;
                    part[r] = fmaf(leaky(pre), w2l[ot], part[r]);
                }
            }
            #pragma unroll
            for (int r = 0; r < 4; ++r) {
                float v = part[r];
                v += __shfl_xor(v, 1, 64);
                v += __shfl_xor(v, 2, 64);
                v += __shfl_xor(v, 4, 64);
                v += __shfl_xor(v, 8, 64);
                part[r] = v;
            }
            if (nloc == 0) {
                const int jr = j16 + quad * 4;
                #pragma unroll
                for (int r = 0; r < 4; ++r)
                    e_out[(size_t)(i0 + ii) * N + jr + r] = part[r] + b2;
            }
        }
    }
}

// ---------------------------------------------------------------------------
// Kernel 3: mask + softmax + aggregation + layernorm. Block = 4 rows.
// ---------------------------------------------------------------------------
__global__ __launch_bounds__(256) void gat_softagg(
    const float* __restrict__ e_in, const int* __restrict__ adj,
    const float* __restrict__ Wh, const float* __restrict__ h,
    const float* __restrict__ ln_g, const float* __restrict__ ln_b,
    float* __restrict__ out)
{
    const int tid  = threadIdx.x;
    const int lane = tid & 63;
    const int wid  = tid >> 6;
    const int i0   = blockIdx.x * 4;
    const int i    = i0 + wid;

    __shared__ float p[4][N];       // 16 KB
    __shared__ float invs[4];
    __shared__ float red[4][4][D];  // [jgroup][row][ch] 4 KB

    // --- per-wave softmax for row i ---------------------------------------
    {
        const float* __restrict__ erow = e_in + (size_t)i * N;
        const int*   __restrict__ arow = adj  + (size_t)i * N;
        float m = -INFINITY;
        #pragma unroll 4
        for (int c = 0; c < N / 64; ++c) {
            int j = c * 64 + lane;
            float v = erow[j];
            if (arow[j] == 0) v = MASK_VAL;
            p[wid][j] = v;
            m = fmaxf(m, v);
        }
        #pragma unroll
        for (int off = 32; off >= 1; off >>= 1) m = fmaxf(m, __shfl_xor(m, off, 64));
        float s = 0.f;
        #pragma unroll 4
        for (int c = 0; c < N / 64; ++c) {
            int j = c * 64 + lane;
            float pv = __expf(p[wid][j] - m);
            p[wid][j] = pv;
            s += pv;
        }
        #pragma unroll
        for (int off = 32; off >= 1; off >>= 1) s += __shfl_xor(s, off, 64);
        if (lane == 0) invs[wid] = 1.f / s;
    }
    __syncthreads();

    // --- aggregation: thread = (channel k, j-group g); Wh load shared ------
    {
        const int k = tid & 63, g = tid >> 6;
        float hp0 = 0.f, hp1 = 0.f, hp2 = 0.f, hp3 = 0.f;
        #pragma unroll 4
        for (int jj = 0; jj < 256; ++jj) {
            const int j = g * 256 + jj;
            const float whv = Wh[(size_t)j * D + k];
            hp0 = fmaf(p[0][j], whv, hp0);
            hp1 = fmaf(p[1][j], whv, hp1);
            hp2 = fmaf(p[2][j], whv, hp2);
            hp3 = fmaf(p[3][j], whv, hp3);
        }
        red[g][0][k] = hp0;
        red[g][1][k] = hp1;
        red[g][2][k] = hp2;
        red[g][3][k] = hp3;
    }
    __syncthreads();

    // --- final: wave wid -> row i; lane = channel --------------------------
    {
        float v = (red[0][wid][lane] + red[1][wid][lane] +
                   red[2][wid][lane] + red[3][wid][lane]) * invs[wid]
                  + h[(size_t)i * D + lane];
        float mu = v;
        #pragma unroll
        for (int off = 32; off >= 1; off >>= 1) mu += __shfl_xor(mu, off, 64);
        mu *= (1.f / D);
        float d = v - mu;
        float var = d * d;
        #pragma unroll
        for (int off = 32; off >= 1; off >>= 1) var += __shfl_xor(var, off, 64);
        var *= (1.f / D);
        out[(size_t)i * D + lane] = d * rsqrtf(var + LN_EPS) * ln_g[lane] + ln_b[lane];
    }
}

// ---------------------------------------------------------------------------
extern "C" void kernel_launch(void* const* d_in, const int* in_sizes, int n_in,
                              void* d_out, int out_size, void* d_ws, size_t ws_size,
                              hipStream_t stream) {
    const float* h       = (const float*)d_in[0];
    const int*   adj     = (const int*)  d_in[1];
    const float* W       = (const float*)d_in[2];
    const float* attn_w1 = (const float*)d_in[3];
    const float* attn_b1 = (const float*)d_in[4];
    const float* attn_w2 = (const float*)d_in[5];
    const float* attn_b2 = (const float*)d_in[6];
    const float* edge_w  = (const float*)d_in[7];
    const float* edge_b  = (const float*)d_in[8];
    const float* ln_g    = (const float*)d_in[9];
    const float* ln_b    = (const float*)d_in[10];
    float* out = (float*)d_out;

    float* ws  = (float*)d_ws;
    float* Wh  = ws + 0 * (N * D);
    float* ejB = ws + 1 * (N * D);
    float* aj  = ws + 2 * (N * D);
    float* ei  = ws + 3 * (N * D);
    float* aiB = ws + 4 * (N * D);
    float* e   = ws + 5 * (N * D);   // N*N floats = 4 MB

    gat_precompute<<<N / 4, 256, 0, stream>>>(h, W, attn_w1, attn_b1, edge_w, edge_b,
                                              Wh, ejB, aj, ei, aiB);
    gat_scores<<<(N / 4) * 4, 256, 0, stream>>>(ejB, aj, ei, aiB,
                                                attn_w1, attn_w2, attn_b2, e);
    gat_softagg<<<N / 4, 256, 0, stream>>>(e, adj, Wh, h, ln_g, ln_b, out);
}